// Round 3
// baseline (1385.449 us; speedup 1.0000x reference)
//
#include <hip/hip_runtime.h>

// Residual VQ (L=4, K=4096, C=256, N=4096) — bf16 screen + exact-candidate refine.
// Pass1: bf16 GEMM (K'=256) with error bound eps = 0.004*||r||.
// Candidates: S~ >= slice_max - M, M = 0.012*||r|| = 3*eps  (superset of exact argmax).
// Refine: exact fp32 dot * inv_k over filtered candidates; overflow -> full scan.

// ws layout (float units):
#define OFF_AS   0          // N x 256 bf16      = 524288 floats
#define OFF_BS   524288     // L*K x 256 bf16    = 2097152 floats
#define OFF_R    2621440    // N x C fp32        = 1048576
#define OFF_INV  3670016    // L x K             = 16384
#define OFF_PV   3686400    // N x 32            = 131072
#define OFF_RN   3817472    // N                 = 4096
#define OFF_CNT  3821568    // N (int)           = 4096
#define OFF_CAND 3825664    // N x 64 (int)      = 262144
#define OFF_CVAL 4087808    // N x 64            = 262144
#define OFF_SSQ  4349952    // L x N             = 16384
#define OFF_SEL  4366336    // N (int)           = 4096
// total 4370432 floats ~ 17.5 MB

#define BETA 0.25f
#define EPSN 1e-12f
#define CAP 64
#define MARGIN 0.012f
#define NEGINF -3.0e38f

typedef __attribute__((ext_vector_type(8))) short short8;
typedef __attribute__((ext_vector_type(4))) float f32x4;

__device__ __forceinline__ unsigned short f2bf(float x) {
  unsigned u = __float_as_uint(x);
  unsigned r = (u + 0x7fffu + ((u >> 16) & 1u)) >> 16;
  return (unsigned short)r;
}

__device__ __forceinline__ void gload16(const void* g, void* s) {
  __builtin_amdgcn_global_load_lds(
      (const __attribute__((address_space(1))) unsigned int*)g,
      (__attribute__((address_space(3))) unsigned int*)s, 16, 0, 0);
}

// ---- transpose z (B,C,H,W) -> r (N=B*HW, C) ----
__global__ __launch_bounds__(256) void k_prep_r(const float* __restrict__ z,
                                                float* __restrict__ r) {
  __shared__ float t[32][33];
  int id = blockIdx.x;
  int b = id >> 8; int rem = id & 255; int ct = rem >> 5; int ht = rem & 31;
  int c0 = ct * 32, h0 = ht * 32;
  int col = threadIdx.x & 31, row0 = threadIdx.x >> 5;
#pragma unroll
  for (int p = 0; p < 4; ++p) {
    int row = row0 + p * 8;
    t[row][col] = z[((b * 256 + c0 + row) << 10) + h0 + col];
  }
  __syncthreads();
#pragma unroll
  for (int p = 0; p < 4; ++p) {
    int row = row0 + p * 8;
    r[(b * 1024 + h0 + row) * 256 + c0 + col] = t[col][row];
  }
}

// ---- per-row inverse norms of codebook ----
__global__ __launch_bounds__(256) void k_prep_inv(const float* __restrict__ cb,
                                                  float* __restrict__ inv) {
  int w = threadIdx.x >> 6, lane = threadIdx.x & 63;
  int row = blockIdx.x * 4 + w;
  float4 v = *(const float4*)(cb + row * 256 + lane * 4);
  float s = v.x * v.x + v.y * v.y + v.z * v.z + v.w * v.w;
#pragma unroll
  for (int off = 32; off; off >>= 1) s += __shfl_xor(s, off);
  if (lane == 0) inv[row] = 1.0f / fmaxf(sqrtf(s), EPSN);
}

// ---- bf16 of normalized codebook, all levels: BS[l*4096+k][c] ----
__global__ __launch_bounds__(256) void k_bsplit_all(const float* __restrict__ cb,
                                                    const float* __restrict__ inv,
                                                    unsigned short* __restrict__ BS) {
  int row = blockIdx.x, c = threadIdx.x;
  float x = cb[(row << 8) + c] * inv[row];
  BS[(row << 8) + c] = f2bf(x);
}

// ---- level-0 A split: bf16(r), row norm, counter reset ----
__global__ __launch_bounds__(256) void k_split_a(const float* __restrict__ r,
                                                 unsigned short* __restrict__ AS,
                                                 float* __restrict__ rnorm,
                                                 int* __restrict__ cnt) {
  __shared__ float wsum[4];
  int n = blockIdx.x, tid = threadIdx.x;
  float x = r[(n << 8) + tid];
  AS[(n << 8) + tid] = f2bf(x);
  float sq = x * x;
  int lane = tid & 63, w = tid >> 6;
#pragma unroll
  for (int off = 32; off; off >>= 1) sq += __shfl_xor(sq, off);
  if (lane == 0) wsum[w] = sq;
  __syncthreads();
  if (tid == 0) {
    rnorm[n] = sqrtf((wsum[0] + wsum[1]) + (wsum[2] + wsum[3]));
    cnt[n] = 0;
  }
}

// ---- bf16 screen GEMM (128x128 tile) + slice max + candidate collection ----
__global__ __launch_bounds__(256) void k_gemm_argmax(
    const unsigned short* __restrict__ AS, const unsigned short* __restrict__ BS,
    float* __restrict__ pval, const float* __restrict__ rnorm,
    int* __restrict__ cnt, int* __restrict__ cand, float* __restrict__ cval) {
  __shared__ unsigned short lA[128 * 64];
  __shared__ unsigned short lB[128 * 64];
  __shared__ float sv[2][2][64];
  __shared__ float scomb[2][64];
  __shared__ float rn_s[2][64];

  int bid = blockIdx.x;
  int wg = (bid & 7) * 128 + (bid >> 3);   // XCD swizzle (1024 % 8 == 0)
  int bm = wg >> 5, bn = wg & 31;
  int mbase = bm * 128, nbase = bn * 128;
  int tid = threadIdx.x;
  int wid = tid >> 6, ln = tid & 63;
  int wr = wid >> 1, wc = wid & 1;
  int grp = ln >> 4, li = ln & 15;

  f32x4 acc[4][4];
#pragma unroll
  for (int i = 0; i < 4; ++i)
#pragma unroll
    for (int j = 0; j < 4; ++j) acc[i][j] = (f32x4){0.f, 0.f, 0.f, 0.f};

  for (int ks = 0; ks < 4; ++ks) {
    __syncthreads();
    int k0 = ks * 64;
#pragma unroll
    for (int i = 0; i < 4; ++i) {
      int idx = i * 256 + tid;
      int row = idx >> 3, cc = idx & 7;
      int src = cc ^ (row & 7);
      gload16(AS + ((mbase + row) << 8) + k0 + src * 8, ((char*)lA) + idx * 16);
    }
#pragma unroll
    for (int i = 0; i < 4; ++i) {
      int idx = i * 256 + tid;
      int row = idx >> 3, cc = idx & 7;
      int src = cc ^ (row & 7);
      gload16(BS + ((nbase + row) << 8) + k0 + src * 8, ((char*)lB) + idx * 16);
    }
    __syncthreads();
#pragma unroll
    for (int kk = 0; kk < 2; ++kk) {
      short8 b[4];
#pragma unroll
      for (int ni = 0; ni < 4; ++ni) {
        int row = wc * 64 + ni * 16 + li;
        int cc = kk * 4 + grp;
        b[ni] = *(const short8*)(((const char*)lB) + row * 128 + (cc ^ (row & 7)) * 16);
      }
#pragma unroll
      for (int mi = 0; mi < 4; ++mi) {
        int row = wr * 64 + mi * 16 + li;
        int cc = kk * 4 + grp;
        short8 a = *(const short8*)(((const char*)lA) + row * 128 + (cc ^ (row & 7)) * 16);
#pragma unroll
        for (int ni = 0; ni < 4; ++ni)
          acc[mi][ni] = __builtin_amdgcn_mfma_f32_16x16x32_bf16(a, b[ni], acc[mi][ni], 0, 0, 0);
      }
    }
  }

  // per-wave 64-col slice max per row (value only)
#pragma unroll
  for (int mi = 0; mi < 4; ++mi) {
#pragma unroll
    for (int reg = 0; reg < 4; ++reg) {
      float v = acc[mi][0][reg];
#pragma unroll
      for (int ni = 1; ni < 4; ++ni) v = fmaxf(v, acc[mi][ni][reg]);
#pragma unroll
      for (int off = 1; off < 16; off <<= 1) v = fmaxf(v, __shfl_xor(v, off));
      if (li == 0) sv[wr][wc][mi * 16 + grp * 4 + reg] = v;
    }
  }
  __syncthreads();
  if (tid < 128) {
    int wr2 = tid >> 6, r64 = tid & 63;
    float m = fmaxf(sv[wr2][0][r64], sv[wr2][1][r64]);
    int n = mbase + wr2 * 64 + r64;
    pval[n * 32 + bn] = m;
    scomb[wr2][r64] = m;
    rn_s[wr2][r64] = rnorm[n];
  }
  __syncthreads();
  // candidate collection vs 128-col slice max
#pragma unroll
  for (int mi = 0; mi < 4; ++mi) {
#pragma unroll
    for (int reg = 0; reg < 4; ++reg) {
      int rl = mi * 16 + grp * 4 + reg;
      float thr = scomb[wr][rl] - MARGIN * rn_s[wr][rl];
      int n = mbase + wr * 64 + rl;
#pragma unroll
      for (int ni = 0; ni < 4; ++ni) {
        float v = acc[mi][ni][reg];
        if (v >= thr) {
          int k = nbase + wc * 64 + ni * 16 + li;
          int pos = atomicAdd(&cnt[n], 1);
          if (pos < CAP) { cand[n * CAP + pos] = k; cval[n * CAP + pos] = v; }
        }
      }
    }
  }
}

// ---- exact refine: filter candidates vs global max, exact fp32 dots ----
__global__ __launch_bounds__(256) void k_refine(
    const float* __restrict__ cb, const float* __restrict__ inv,
    const float* __restrict__ r, const float* __restrict__ pval,
    const float* __restrict__ rnorm, const int* __restrict__ cnt,
    const int* __restrict__ cand, const float* __restrict__ cval,
    float* __restrict__ out_idx, int* __restrict__ idxsel, int l) {
  __shared__ float rrow[256];
  __shared__ float wsum[4];
  __shared__ float gm_s;
  __shared__ int list[CAP];
  __shared__ int lcnt;
  __shared__ float bvv[256];
  __shared__ int bkk[256];
  int n = blockIdx.x, tid = threadIdx.x;
  rrow[tid] = r[(n << 8) + tid];
  if (tid == 0) lcnt = 0;
  if (tid < 64) {
    float v = (tid < 32) ? pval[n * 32 + tid] : NEGINF;
#pragma unroll
    for (int off = 1; off < 64; off <<= 1) v = fmaxf(v, __shfl_xor(v, off));
    if (tid == 0) gm_s = v;
  }
  __syncthreads();
  int c = cnt[n];
  const float* cbl = cb + (l << 20);   // l*4096*256
  const float* invl = inv + (l << 12);
  float bv = NEGINF; int bk = 0x7fffffff;
  if (c <= CAP) {
    float thr = gm_s - MARGIN * rnorm[n];
    if (tid < c) {
      float v = cval[n * CAP + tid];
      if (v >= thr) { int p = atomicAdd(&lcnt, 1); list[p] = cand[n * CAP + tid]; }
    }
    __syncthreads();
    int m = lcnt;
    for (int j = 0; j < m; ++j) {
      int k = list[j];
      float p = rrow[tid] * cbl[(k << 8) + tid];
      int lane = tid & 63, w = tid >> 6;
#pragma unroll
      for (int off = 32; off; off >>= 1) p += __shfl_xor(p, off);
      if (lane == 0) wsum[w] = p;
      __syncthreads();
      if (tid == 0) {
        float s = ((wsum[0] + wsum[1]) + (wsum[2] + wsum[3])) * invl[k];
        if (s > bv || (s == bv && k < bk)) { bv = s; bk = k; }
      }
      __syncthreads();
    }
    if (tid == 0) { out_idx[(l << 12) + n] = (float)bk; idxsel[n] = bk; }
  } else {
    // overflow fallback: exact scan of all 4096 codes (never triggers on real data)
    for (int k = tid; k < 4096; k += 256) {
      float s = 0.f;
      for (int cc2 = 0; cc2 < 256; ++cc2) s = fmaf(rrow[cc2], cbl[(k << 8) + cc2], s);
      s *= invl[k];
      if (s > bv || (s == bv && k < bk)) { bv = s; bk = k; }
    }
    bvv[tid] = bv; bkk[tid] = bk;
    __syncthreads();
    if (tid == 0) {
      for (int t = 1; t < 256; ++t) {
        float ov = bvv[t]; int oi = bkk[t];
        if (ov > bv || (ov == bv && oi < bk)) { bv = ov; bk = oi; }
      }
      out_idx[(l << 12) + n] = (float)bk; idxsel[n] = bk;
    }
  }
}

// ---- residual update + next-level A split + norms + counter reset ----
__global__ __launch_bounds__(256) void k_update(const float* __restrict__ cb,
                                                float* __restrict__ r,
                                                unsigned short* __restrict__ AS,
                                                float* __restrict__ rnorm,
                                                int* __restrict__ cnt,
                                                float* __restrict__ ssq,
                                                const int* __restrict__ idxsel, int l) {
  __shared__ float wsum[4];
  int n = blockIdx.x, tid = threadIdx.x;
  int ii = idxsel[n];
  float e = cb[((l * 4096 + ii) << 8) + tid];
  float rv = r[(n << 8) + tid] - e;
  r[(n << 8) + tid] = rv;
  AS[(n << 8) + tid] = f2bf(rv);
  float sq = rv * rv;
  int lane = tid & 63, w = tid >> 6;
#pragma unroll
  for (int off = 32; off; off >>= 1) sq += __shfl_xor(sq, off);
  if (lane == 0) wsum[w] = sq;
  __syncthreads();
  if (tid == 0) {
    float tot = (wsum[0] + wsum[1]) + (wsum[2] + wsum[3]);
    ssq[(l << 12) + n] = tot;
    rnorm[n] = sqrtf(tot);
    cnt[n] = 0;
  }
}

// ---- qloss: fixed-order reduction ----
__global__ __launch_bounds__(256) void k_qloss(const float* __restrict__ ssq,
                                               float* __restrict__ out) {
  __shared__ float wsum[4];
  int tid = threadIdx.x;
  float q = 0.f;
  for (int l = 0; l < 4; ++l) {
    float p = 0.f;
#pragma unroll
    for (int i = 0; i < 16; ++i) p += ssq[l * 4096 + i * 256 + tid];
    int lane = tid & 63, w = tid >> 6;
#pragma unroll
    for (int off = 32; off; off >>= 1) p += __shfl_xor(p, off);
    if (lane == 0) wsum[w] = p;
    __syncthreads();
    float tot = (wsum[0] + wsum[1]) + (wsum[2] + wsum[3]);
    q += BETA * (tot * (1.0f / (4096.0f * 256.0f)));
    __syncthreads();
  }
  if (tid == 0) out[1048576 + 16384] = q;
}

// ---- z_q_st = z - residual_final ----
__global__ __launch_bounds__(256) void k_writeq(const float* __restrict__ z,
                                                const float* __restrict__ r,
                                                float* __restrict__ out) {
  __shared__ float t[32][33];
  int id = blockIdx.x;
  int b = id >> 8; int rem = id & 255; int ct = rem >> 5; int ht = rem & 31;
  int c0 = ct * 32, h0 = ht * 32;
  int col = threadIdx.x & 31, row0 = threadIdx.x >> 5;
#pragma unroll
  for (int p = 0; p < 4; ++p) {
    int row = row0 + p * 8;
    t[row][col] = r[(b * 1024 + h0 + row) * 256 + c0 + col];
  }
  __syncthreads();
#pragma unroll
  for (int p = 0; p < 4; ++p) {
    int row = row0 + p * 8;
    int o = ((b * 256 + c0 + row) << 10) + h0 + col;
    out[o] = z[o] - t[col][row];
  }
}

extern "C" void kernel_launch(void* const* d_in, const int* in_sizes, int n_in,
                              void* d_out, int out_size, void* d_ws, size_t ws_size,
                              hipStream_t stream) {
  const float* z  = (const float*)d_in[0];
  const float* cb = (const float*)d_in[1];
  float* out = (float*)d_out;
  float* ws  = (float*)d_ws;

  unsigned short* AS = (unsigned short*)(ws + OFF_AS);
  unsigned short* BS = (unsigned short*)(ws + OFF_BS);
  float* r     = ws + OFF_R;
  float* inv   = ws + OFF_INV;
  float* pval  = ws + OFF_PV;
  float* rnorm = ws + OFF_RN;
  int*   cnt   = (int*)(ws + OFF_CNT);
  int*   cand  = (int*)(ws + OFF_CAND);
  float* cval  = ws + OFF_CVAL;
  float* ssq   = ws + OFF_SSQ;
  int*   idxsel= (int*)(ws + OFF_SEL);

  k_prep_r<<<1024, 256, 0, stream>>>(z, r);
  k_prep_inv<<<4096, 256, 0, stream>>>(cb, inv);
  k_bsplit_all<<<16384, 256, 0, stream>>>(cb, inv, BS);
  k_split_a<<<4096, 256, 0, stream>>>(r, AS, rnorm, cnt);
  for (int l = 0; l < 4; ++l) {
    k_gemm_argmax<<<1024, 256, 0, stream>>>(AS, BS + (size_t)l * 4096 * 256,
                                            pval, rnorm, cnt, cand, cval);
    k_refine<<<4096, 256, 0, stream>>>(cb, inv, r, pval, rnorm, cnt, cand, cval,
                                       out + 1048576, idxsel, l);
    k_update<<<4096, 256, 0, stream>>>(cb, r, AS, rnorm, cnt, ssq, idxsel, l);
  }
  k_qloss<<<1, 256, 0, stream>>>(ssq, out);
  k_writeq<<<1024, 256, 0, stream>>>(z, r, out);
}

// Round 4
// 346.327 us; speedup vs baseline: 4.0004x; 4.0004x over previous
//
#include <hip/hip_runtime.h>

// Residual VQ (L=4, K=4096, C=256, N=4096) — bf16 screen + exact-candidate refine.
// Pass1: bf16 GEMM (K'=256) with error bound eps = 0.004*||r||.
// Candidates: S~ >= slice_max - M, M = 0.012*||r|| >= 3*eps (superset of exact argmax).
// Refine: filter vs global screened max, exact fp32 dot * inv_k, wave-parallel.
// Overflow (cnt > 256, ~never): coalesced wave-per-row full exact scan.

// ws layout (float units):
#define OFF_AS   0          // N x 256 bf16      = 524288 floats
#define OFF_BS   524288     // L*K x 256 bf16    = 2097152 floats
#define OFF_R    2621440    // N x C fp32        = 1048576
#define OFF_INV  3670016    // L x K             = 16384
#define OFF_PV   3686400    // N x 32            = 131072
#define OFF_RN   3817472    // N                 = 4096
#define OFF_CNT  3821568    // N (int)           = 4096
#define OFF_CAND 3825664    // N x 256 (int)     = 1048576
#define OFF_CVAL 4874240    // N x 256           = 1048576
#define OFF_SSQ  5922816    // L x N             = 16384
// total 5939200 floats ~ 23.8 MB

#define BETA 0.25f
#define EPSN 1e-12f
#define CAP 256
#define MARGIN 0.012f
#define NEGINF -3.0e38f

typedef __attribute__((ext_vector_type(8))) short short8;
typedef __attribute__((ext_vector_type(4))) float f32x4;

__device__ __forceinline__ unsigned short f2bf(float x) {
  unsigned u = __float_as_uint(x);
  unsigned r = (u + 0x7fffu + ((u >> 16) & 1u)) >> 16;
  return (unsigned short)r;
}

__device__ __forceinline__ void gload16(const void* g, void* s) {
  __builtin_amdgcn_global_load_lds(
      (const __attribute__((address_space(1))) unsigned int*)g,
      (__attribute__((address_space(3))) unsigned int*)s, 16, 0, 0);
}

// ---- transpose z (B,C,H,W) -> r (N=B*HW, C) ----
__global__ __launch_bounds__(256) void k_prep_r(const float* __restrict__ z,
                                                float* __restrict__ r) {
  __shared__ float t[32][33];
  int id = blockIdx.x;
  int b = id >> 8; int rem = id & 255; int ct = rem >> 5; int ht = rem & 31;
  int c0 = ct * 32, h0 = ht * 32;
  int col = threadIdx.x & 31, row0 = threadIdx.x >> 5;
#pragma unroll
  for (int p = 0; p < 4; ++p) {
    int row = row0 + p * 8;
    t[row][col] = z[((b * 256 + c0 + row) << 10) + h0 + col];
  }
  __syncthreads();
#pragma unroll
  for (int p = 0; p < 4; ++p) {
    int row = row0 + p * 8;
    r[(b * 1024 + h0 + row) * 256 + c0 + col] = t[col][row];
  }
}

// ---- per-row inverse norms of codebook ----
__global__ __launch_bounds__(256) void k_prep_inv(const float* __restrict__ cb,
                                                  float* __restrict__ inv) {
  int w = threadIdx.x >> 6, lane = threadIdx.x & 63;
  int row = blockIdx.x * 4 + w;
  float4 v = *(const float4*)(cb + row * 256 + lane * 4);
  float s = v.x * v.x + v.y * v.y + v.z * v.z + v.w * v.w;
#pragma unroll
  for (int off = 32; off; off >>= 1) s += __shfl_xor(s, off);
  if (lane == 0) inv[row] = 1.0f / fmaxf(sqrtf(s), EPSN);
}

// ---- bf16 of normalized codebook, all levels ----
__global__ __launch_bounds__(256) void k_bsplit_all(const float* __restrict__ cb,
                                                    const float* __restrict__ inv,
                                                    unsigned short* __restrict__ BS) {
  int row = blockIdx.x, c = threadIdx.x;
  float x = cb[(row << 8) + c] * inv[row];
  BS[(row << 8) + c] = f2bf(x);
}

// ---- level-0 A split: bf16(r), row norm, counter reset ----
__global__ __launch_bounds__(256) void k_split_a(const float* __restrict__ r,
                                                 unsigned short* __restrict__ AS,
                                                 float* __restrict__ rnorm,
                                                 int* __restrict__ cnt) {
  __shared__ float wsum[4];
  int n = blockIdx.x, tid = threadIdx.x;
  float x = r[(n << 8) + tid];
  AS[(n << 8) + tid] = f2bf(x);
  float sq = x * x;
  int lane = tid & 63, w = tid >> 6;
#pragma unroll
  for (int off = 32; off; off >>= 1) sq += __shfl_xor(sq, off);
  if (lane == 0) wsum[w] = sq;
  __syncthreads();
  if (tid == 0) {
    rnorm[n] = sqrtf((wsum[0] + wsum[1]) + (wsum[2] + wsum[3]));
    cnt[n] = 0;
  }
}

// ---- bf16 screen GEMM (128x128 tile) + slice max + candidate collection ----
__global__ __launch_bounds__(256) void k_gemm_argmax(
    const unsigned short* __restrict__ AS, const unsigned short* __restrict__ BS,
    float* __restrict__ pval, const float* __restrict__ rnorm,
    int* __restrict__ cnt, int* __restrict__ cand, float* __restrict__ cval) {
  __shared__ unsigned short lA[128 * 64];
  __shared__ unsigned short lB[128 * 64];
  __shared__ float sv[2][2][64];
  __shared__ float scomb[2][64];
  __shared__ float rn_s[2][64];

  int bid = blockIdx.x;
  int wg = (bid & 7) * 128 + (bid >> 3);   // XCD swizzle (1024 % 8 == 0)
  int bm = wg >> 5, bn = wg & 31;
  int mbase = bm * 128, nbase = bn * 128;
  int tid = threadIdx.x;
  int wid = tid >> 6, ln = tid & 63;
  int wr = wid >> 1, wc = wid & 1;
  int grp = ln >> 4, li = ln & 15;

  f32x4 acc[4][4];
#pragma unroll
  for (int i = 0; i < 4; ++i)
#pragma unroll
    for (int j = 0; j < 4; ++j) acc[i][j] = (f32x4){0.f, 0.f, 0.f, 0.f};

  for (int ks = 0; ks < 4; ++ks) {
    __syncthreads();
    int k0 = ks * 64;
#pragma unroll
    for (int i = 0; i < 4; ++i) {
      int idx = i * 256 + tid;
      int row = idx >> 3, cc = idx & 7;
      int src = cc ^ (row & 7);
      gload16(AS + ((mbase + row) << 8) + k0 + src * 8, ((char*)lA) + idx * 16);
    }
#pragma unroll
    for (int i = 0; i < 4; ++i) {
      int idx = i * 256 + tid;
      int row = idx >> 3, cc = idx & 7;
      int src = cc ^ (row & 7);
      gload16(BS + ((nbase + row) << 8) + k0 + src * 8, ((char*)lB) + idx * 16);
    }
    __syncthreads();
#pragma unroll
    for (int kk = 0; kk < 2; ++kk) {
      short8 b[4];
#pragma unroll
      for (int ni = 0; ni < 4; ++ni) {
        int row = wc * 64 + ni * 16 + li;
        int cc = kk * 4 + grp;
        b[ni] = *(const short8*)(((const char*)lB) + row * 128 + (cc ^ (row & 7)) * 16);
      }
#pragma unroll
      for (int mi = 0; mi < 4; ++mi) {
        int row = wr * 64 + mi * 16 + li;
        int cc = kk * 4 + grp;
        short8 a = *(const short8*)(((const char*)lA) + row * 128 + (cc ^ (row & 7)) * 16);
#pragma unroll
        for (int ni = 0; ni < 4; ++ni)
          acc[mi][ni] = __builtin_amdgcn_mfma_f32_16x16x32_bf16(a, b[ni], acc[mi][ni], 0, 0, 0);
      }
    }
  }

  // per-wave 64-col slice max per row (value only)
#pragma unroll
  for (int mi = 0; mi < 4; ++mi) {
#pragma unroll
    for (int reg = 0; reg < 4; ++reg) {
      float v = acc[mi][0][reg];
#pragma unroll
      for (int ni = 1; ni < 4; ++ni) v = fmaxf(v, acc[mi][ni][reg]);
#pragma unroll
      for (int off = 1; off < 16; off <<= 1) v = fmaxf(v, __shfl_xor(v, off));
      if (li == 0) sv[wr][wc][mi * 16 + grp * 4 + reg] = v;
    }
  }
  __syncthreads();
  if (tid < 128) {
    int wr2 = tid >> 6, r64 = tid & 63;
    float m = fmaxf(sv[wr2][0][r64], sv[wr2][1][r64]);
    int n = mbase + wr2 * 64 + r64;
    pval[n * 32 + bn] = m;
    scomb[wr2][r64] = m;
    rn_s[wr2][r64] = rnorm[n];
  }
  __syncthreads();
  // candidate collection vs 128-col slice max
#pragma unroll
  for (int mi = 0; mi < 4; ++mi) {
#pragma unroll
    for (int reg = 0; reg < 4; ++reg) {
      int rl = mi * 16 + grp * 4 + reg;
      float thr = scomb[wr][rl] - MARGIN * rn_s[wr][rl];
      int n = mbase + wr * 64 + rl;
#pragma unroll
      for (int ni = 0; ni < 4; ++ni) {
        float v = acc[mi][ni][reg];
        if (v >= thr) {
          int k = nbase + wc * 64 + ni * 16 + li;
          int pos = atomicAdd(&cnt[n], 1);
          if (pos < CAP) { cand[n * CAP + pos] = k; cval[n * CAP + pos] = v; }
        }
      }
    }
  }
}

// ---- fused: filter vs global max -> wave-parallel exact dots -> argmax
//      -> residual update + next A split + norms + counter reset ----
__global__ __launch_bounds__(256) void k_refine_update(
    const float* __restrict__ cb, const float* __restrict__ inv,
    float* __restrict__ r, const float* __restrict__ pval,
    float* __restrict__ rnorm, int* __restrict__ cnt,
    const int* __restrict__ cand, const float* __restrict__ cval,
    unsigned short* __restrict__ AS, float* __restrict__ ssq,
    float* __restrict__ out_idx, int l) {
  __shared__ float rrow[256];
  __shared__ float gm_s;
  __shared__ int list[CAP];
  __shared__ int lcnt;
  __shared__ float wbv[4];
  __shared__ int wbk[4];
  __shared__ int sbk;
  __shared__ float wsum[4];

  int n = blockIdx.x, tid = threadIdx.x;
  int w = tid >> 6, lane = tid & 63;
  rrow[tid] = r[(n << 8) + tid];
  if (tid == 0) lcnt = 0;
  if (tid < 64) {
    float v = (lane < 32) ? pval[n * 32 + lane] : NEGINF;
#pragma unroll
    for (int off = 1; off < 32; off <<= 1) v = fmaxf(v, __shfl_xor(v, off));
    if (tid == 0) gm_s = v;
  }
  __syncthreads();

  int c = cnt[n];
  const float* cbl = cb + ((size_t)l << 20);
  const float* invl = inv + (l << 12);
  float bv = NEGINF; int bk = 0x7fffffff;
  float4 rv4 = *(const float4*)(rrow + lane * 4);

  if (c <= CAP) {
    float thr = gm_s - MARGIN * rnorm[n];
    if (tid < c) {
      float v = cval[n * CAP + tid];
      if (v >= thr) { int p = atomicAdd(&lcnt, 1); list[p] = cand[n * CAP + tid]; }
    }
    __syncthreads();
    int m = lcnt;
    for (int j = w; j < m; j += 4) {          // wave-parallel exact dots
      int k = list[j];
      float4 e4 = *(const float4*)(cbl + ((size_t)k << 8) + lane * 4);
      float p = rv4.x * e4.x + rv4.y * e4.y + rv4.z * e4.z + rv4.w * e4.w;
#pragma unroll
      for (int off = 32; off; off >>= 1) p += __shfl_xor(p, off);
      float s = p * invl[k];
      if (s > bv || (s == bv && k < bk)) { bv = s; bk = k; }
    }
  } else {
    __syncthreads();                           // keep barrier count uniform
    // coalesced full exact scan: wave w handles rows 4*kk + w
    for (int kk = 0; kk < 1024; ++kk) {
      int k = kk * 4 + w;
      float4 e4 = *(const float4*)(cbl + ((size_t)k << 8) + lane * 4);
      float p = rv4.x * e4.x + rv4.y * e4.y + rv4.z * e4.z + rv4.w * e4.w;
#pragma unroll
      for (int off = 32; off; off >>= 1) p += __shfl_xor(p, off);
      float s = p * invl[k];
      if (s > bv || (s == bv && k < bk)) { bv = s; bk = k; }
    }
  }
  if (lane == 0) { wbv[w] = bv; wbk[w] = bk; }
  __syncthreads();
  if (tid == 0) {
    float v0 = wbv[0]; int i0 = wbk[0];
#pragma unroll
    for (int ww = 1; ww < 4; ++ww) {
      float ov = wbv[ww]; int oi = wbk[ww];
      if (ov > v0 || (ov == v0 && oi < i0)) { v0 = ov; i0 = oi; }
    }
    sbk = i0;
    out_idx[(l << 12) + n] = (float)i0;
  }
  __syncthreads();

  // ---- residual update + next-level A split ----
  int ii = sbk;
  float e = cbl[((size_t)ii << 8) + tid];
  float rvv = rrow[tid] - e;
  r[(n << 8) + tid] = rvv;
  AS[(n << 8) + tid] = f2bf(rvv);
  float sq = rvv * rvv;
#pragma unroll
  for (int off = 32; off; off >>= 1) sq += __shfl_xor(sq, off);
  if (lane == 0) wsum[w] = sq;
  __syncthreads();
  if (tid == 0) {
    float tot = (wsum[0] + wsum[1]) + (wsum[2] + wsum[3]);
    ssq[(l << 12) + n] = tot;
    rnorm[n] = sqrtf(tot);
    cnt[n] = 0;
  }
}

// ---- qloss: fixed-order reduction ----
__global__ __launch_bounds__(256) void k_qloss(const float* __restrict__ ssq,
                                               float* __restrict__ out) {
  __shared__ float wsum[4];
  int tid = threadIdx.x;
  float q = 0.f;
  for (int l = 0; l < 4; ++l) {
    float p = 0.f;
#pragma unroll
    for (int i = 0; i < 16; ++i) p += ssq[l * 4096 + i * 256 + tid];
    int lane = tid & 63, w = tid >> 6;
#pragma unroll
    for (int off = 32; off; off >>= 1) p += __shfl_xor(p, off);
    if (lane == 0) wsum[w] = p;
    __syncthreads();
    float tot = (wsum[0] + wsum[1]) + (wsum[2] + wsum[3]);
    q += BETA * (tot * (1.0f / (4096.0f * 256.0f)));
    __syncthreads();
  }
  if (tid == 0) out[1048576 + 16384] = q;
}

// ---- z_q_st = z - residual_final ----
__global__ __launch_bounds__(256) void k_writeq(const float* __restrict__ z,
                                                const float* __restrict__ r,
                                                float* __restrict__ out) {
  __shared__ float t[32][33];
  int id = blockIdx.x;
  int b = id >> 8; int rem = id & 255; int ct = rem >> 5; int ht = rem & 31;
  int c0 = ct * 32, h0 = ht * 32;
  int col = threadIdx.x & 31, row0 = threadIdx.x >> 5;
#pragma unroll
  for (int p = 0; p < 4; ++p) {
    int row = row0 + p * 8;
    t[row][col] = r[(b * 1024 + h0 + row) * 256 + c0 + col];
  }
  __syncthreads();
#pragma unroll
  for (int p = 0; p < 4; ++p) {
    int row = row0 + p * 8;
    int o = ((b * 256 + c0 + row) << 10) + h0 + col;
    out[o] = z[o] - t[col][row];
  }
}

extern "C" void kernel_launch(void* const* d_in, const int* in_sizes, int n_in,
                              void* d_out, int out_size, void* d_ws, size_t ws_size,
                              hipStream_t stream) {
  const float* z  = (const float*)d_in[0];
  const float* cb = (const float*)d_in[1];
  float* out = (float*)d_out;
  float* ws  = (float*)d_ws;

  unsigned short* AS = (unsigned short*)(ws + OFF_AS);
  unsigned short* BS = (unsigned short*)(ws + OFF_BS);
  float* r     = ws + OFF_R;
  float* inv   = ws + OFF_INV;
  float* pval  = ws + OFF_PV;
  float* rnorm = ws + OFF_RN;
  int*   cnt   = (int*)(ws + OFF_CNT);
  int*   cand  = (int*)(ws + OFF_CAND);
  float* cval  = ws + OFF_CVAL;
  float* ssq   = ws + OFF_SSQ;

  k_prep_r<<<1024, 256, 0, stream>>>(z, r);
  k_prep_inv<<<4096, 256, 0, stream>>>(cb, inv);
  k_bsplit_all<<<16384, 256, 0, stream>>>(cb, inv, BS);
  k_split_a<<<4096, 256, 0, stream>>>(r, AS, rnorm, cnt);
  for (int l = 0; l < 4; ++l) {
    k_gemm_argmax<<<1024, 256, 0, stream>>>(AS, BS + (size_t)l * 4096 * 256,
                                            pval, rnorm, cnt, cand, cval);
    k_refine_update<<<4096, 256, 0, stream>>>(cb, inv, r, pval, rnorm, cnt,
                                              cand, cval, AS, ssq,
                                              out + 1048576, l);
  }
  k_qloss<<<1, 256, 0, stream>>>(ssq, out);
  k_writeq<<<1024, 256, 0, stream>>>(z, r, out);
}

// Round 5
// 184.726 us; speedup vs baseline: 7.5000x; 1.8748x over previous
//
#include <hip/hip_runtime.h>

// Residual VQ (L=4, K=4096, C=256, N=4096) — bf16 screen + exact-candidate refine.
// Pass1: bf16 GEMM (K'=256) with error bound eps = 0.004*||r||.
// Candidates: S~ >= slice_max - M, M = 0.012*||r|| >= 3*eps (superset of exact argmax).
// Collection: per-row LDS compaction, then ONE global atomic per row per block.
// Refine: filter vs global screened max, exact fp32 dot * inv_k, wave-parallel.
// Overflow (cnt > CAP, ~never): coalesced wave-per-row full exact scan.

// ws layout (float units):
#define OFF_AS   0          // N x 256 bf16      = 524288 floats
#define OFF_BS   524288     // L*K x 256 bf16    = 2097152 floats
#define OFF_R    2621440    // N x C fp32        = 1048576
#define OFF_INV  3670016    // L x K             = 16384
#define OFF_PV   3686400    // N x 32            = 131072
#define OFF_RN   3817472    // N                 = 4096
#define OFF_CNT  3821568    // N (int)           = 4096
#define OFF_CAND 3825664    // N x 256 (int)     = 1048576
#define OFF_CVAL 4874240    // N x 256           = 1048576
#define OFF_SSQ  5922816    // L x N             = 16384
// total 5939200 floats ~ 23.8 MB

#define BETA 0.25f
#define EPSN 1e-12f
#define CAP 256
#define SLC 16              // LDS candidate slots per row per 128-col slice
#define OVF (1 << 20)       // overflow marker
#define MARGIN 0.012f
#define NEGINF -3.0e38f

typedef __attribute__((ext_vector_type(8))) short short8;
typedef __attribute__((ext_vector_type(4))) float f32x4;

__device__ __forceinline__ unsigned short f2bf(float x) {
  unsigned u = __float_as_uint(x);
  unsigned r = (u + 0x7fffu + ((u >> 16) & 1u)) >> 16;
  return (unsigned short)r;
}

__device__ __forceinline__ void gload16(const void* g, void* s) {
  __builtin_amdgcn_global_load_lds(
      (const __attribute__((address_space(1))) unsigned int*)g,
      (__attribute__((address_space(3))) unsigned int*)s, 16, 0, 0);
}

// ---- transpose z (B,C,H,W) -> r (N=B*HW, C) ----
__global__ __launch_bounds__(256) void k_prep_r(const float* __restrict__ z,
                                                float* __restrict__ r) {
  __shared__ float t[32][33];
  int id = blockIdx.x;
  int b = id >> 8; int rem = id & 255; int ct = rem >> 5; int ht = rem & 31;
  int c0 = ct * 32, h0 = ht * 32;
  int col = threadIdx.x & 31, row0 = threadIdx.x >> 5;
#pragma unroll
  for (int p = 0; p < 4; ++p) {
    int row = row0 + p * 8;
    t[row][col] = z[((b * 256 + c0 + row) << 10) + h0 + col];
  }
  __syncthreads();
#pragma unroll
  for (int p = 0; p < 4; ++p) {
    int row = row0 + p * 8;
    r[(b * 1024 + h0 + row) * 256 + c0 + col] = t[col][row];
  }
}

// ---- per-row inverse norms of codebook ----
__global__ __launch_bounds__(256) void k_prep_inv(const float* __restrict__ cb,
                                                  float* __restrict__ inv) {
  int w = threadIdx.x >> 6, lane = threadIdx.x & 63;
  int row = blockIdx.x * 4 + w;
  float4 v = *(const float4*)(cb + row * 256 + lane * 4);
  float s = v.x * v.x + v.y * v.y + v.z * v.z + v.w * v.w;
#pragma unroll
  for (int off = 32; off; off >>= 1) s += __shfl_xor(s, off);
  if (lane == 0) inv[row] = 1.0f / fmaxf(sqrtf(s), EPSN);
}

// ---- bf16 of normalized codebook, all levels ----
__global__ __launch_bounds__(256) void k_bsplit_all(const float* __restrict__ cb,
                                                    const float* __restrict__ inv,
                                                    unsigned short* __restrict__ BS) {
  int row = blockIdx.x, c = threadIdx.x;
  float x = cb[(row << 8) + c] * inv[row];
  BS[(row << 8) + c] = f2bf(x);
}

// ---- level-0 A split: bf16(r), row norm, counter reset ----
__global__ __launch_bounds__(256) void k_split_a(const float* __restrict__ r,
                                                 unsigned short* __restrict__ AS,
                                                 float* __restrict__ rnorm,
                                                 int* __restrict__ cnt) {
  __shared__ float wsum[4];
  int n = blockIdx.x, tid = threadIdx.x;
  float x = r[(n << 8) + tid];
  AS[(n << 8) + tid] = f2bf(x);
  float sq = x * x;
  int lane = tid & 63, w = tid >> 6;
#pragma unroll
  for (int off = 32; off; off >>= 1) sq += __shfl_xor(sq, off);
  if (lane == 0) wsum[w] = sq;
  __syncthreads();
  if (tid == 0) {
    rnorm[n] = sqrtf((wsum[0] + wsum[1]) + (wsum[2] + wsum[3]));
    cnt[n] = 0;
  }
}

// ---- bf16 screen GEMM (128x128 tile) + slice max + LDS-compacted candidates ----
__global__ __launch_bounds__(256) void k_gemm_argmax(
    const unsigned short* __restrict__ AS, const unsigned short* __restrict__ BS,
    float* __restrict__ pval, const float* __restrict__ rnorm,
    int* __restrict__ cnt, int* __restrict__ cand, float* __restrict__ cval) {
  __shared__ unsigned short lA[128 * 64];
  __shared__ unsigned short lB[128 * 64];
  __shared__ float sv[2][2][64];
  __shared__ float scomb[2][64];
  __shared__ float rn_s[2][64];
  __shared__ int   lcnt[128];
  __shared__ int   lck[128][SLC];
  __shared__ float lcv[128][SLC];

  int bid = blockIdx.x;
  int wg = (bid & 7) * 128 + (bid >> 3);   // XCD swizzle (1024 % 8 == 0)
  int bm = wg >> 5, bn = wg & 31;
  int mbase = bm * 128, nbase = bn * 128;
  int tid = threadIdx.x;
  int wid = tid >> 6, ln = tid & 63;
  int wr = wid >> 1, wc = wid & 1;
  int grp = ln >> 4, li = ln & 15;

  f32x4 acc[4][4];
#pragma unroll
  for (int i = 0; i < 4; ++i)
#pragma unroll
    for (int j = 0; j < 4; ++j) acc[i][j] = (f32x4){0.f, 0.f, 0.f, 0.f};

  for (int ks = 0; ks < 4; ++ks) {
    __syncthreads();
    int k0 = ks * 64;
#pragma unroll
    for (int i = 0; i < 4; ++i) {
      int idx = i * 256 + tid;
      int row = idx >> 3, cc = idx & 7;
      int src = cc ^ (row & 7);
      gload16(AS + ((mbase + row) << 8) + k0 + src * 8, ((char*)lA) + idx * 16);
    }
#pragma unroll
    for (int i = 0; i < 4; ++i) {
      int idx = i * 256 + tid;
      int row = idx >> 3, cc = idx & 7;
      int src = cc ^ (row & 7);
      gload16(BS + ((nbase + row) << 8) + k0 + src * 8, ((char*)lB) + idx * 16);
    }
    __syncthreads();
#pragma unroll
    for (int kk = 0; kk < 2; ++kk) {
      short8 b[4];
#pragma unroll
      for (int ni = 0; ni < 4; ++ni) {
        int row = wc * 64 + ni * 16 + li;
        int cc = kk * 4 + grp;
        b[ni] = *(const short8*)(((const char*)lB) + row * 128 + (cc ^ (row & 7)) * 16);
      }
#pragma unroll
      for (int mi = 0; mi < 4; ++mi) {
        int row = wr * 64 + mi * 16 + li;
        int cc = kk * 4 + grp;
        short8 a = *(const short8*)(((const char*)lA) + row * 128 + (cc ^ (row & 7)) * 16);
#pragma unroll
        for (int ni = 0; ni < 4; ++ni)
          acc[mi][ni] = __builtin_amdgcn_mfma_f32_16x16x32_bf16(a, b[ni], acc[mi][ni], 0, 0, 0);
      }
    }
  }

  // per-wave 64-col slice max per row (value only)
#pragma unroll
  for (int mi = 0; mi < 4; ++mi) {
#pragma unroll
    for (int reg = 0; reg < 4; ++reg) {
      float v = acc[mi][0][reg];
#pragma unroll
      for (int ni = 1; ni < 4; ++ni) v = fmaxf(v, acc[mi][ni][reg]);
#pragma unroll
      for (int off = 1; off < 16; off <<= 1) v = fmaxf(v, __shfl_xor(v, off));
      if (li == 0) sv[wr][wc][mi * 16 + grp * 4 + reg] = v;
    }
  }
  __syncthreads();
  if (tid < 128) {
    int wr2 = tid >> 6, r64 = tid & 63;
    float m = fmaxf(sv[wr2][0][r64], sv[wr2][1][r64]);
    int n = mbase + wr2 * 64 + r64;
    pval[n * 32 + bn] = m;
    scomb[wr2][r64] = m;
    rn_s[wr2][r64] = rnorm[n];
    lcnt[tid] = 0;
  }
  __syncthreads();
  // candidate collection into per-row LDS buffers (LDS atomics only)
#pragma unroll
  for (int mi = 0; mi < 4; ++mi) {
#pragma unroll
    for (int reg = 0; reg < 4; ++reg) {
      int rl = mi * 16 + grp * 4 + reg;
      float thr = scomb[wr][rl] - MARGIN * rn_s[wr][rl];
      int rloc = wr * 64 + rl;
#pragma unroll
      for (int ni = 0; ni < 4; ++ni) {
        float v = acc[mi][ni][reg];
        if (v >= thr) {
          int pos = atomicAdd(&lcnt[rloc], 1);
          if (pos < SLC) {
            lck[rloc][pos] = nbase + wc * 64 + ni * 16 + li;
            lcv[rloc][pos] = v;
          }
        }
      }
    }
  }
  __syncthreads();
  // write-out: one global atomic per row (parallel across 128 threads)
  if (tid < 128) {
    int rloc = tid;
    int n = mbase + rloc;
    int raw = lcnt[rloc];
    int lc = raw < SLC ? raw : SLC;
    int add = raw > SLC ? (lc + OVF) : lc;
    if (add > 0) {
      int base = atomicAdd(&cnt[n], add);
      for (int j = 0; j < lc; ++j) {
        int pos = base + j;
        if (pos < CAP) {
          cand[n * CAP + pos] = lck[rloc][j];
          cval[n * CAP + pos] = lcv[rloc][j];
        }
      }
    }
  }
}

// ---- fused: filter vs global max -> wave-parallel exact dots -> argmax
//      -> residual update + next A split + norms + counter reset ----
__global__ __launch_bounds__(256) void k_refine_update(
    const float* __restrict__ cb, const float* __restrict__ inv,
    float* __restrict__ r, const float* __restrict__ pval,
    float* __restrict__ rnorm, int* __restrict__ cnt,
    const int* __restrict__ cand, const float* __restrict__ cval,
    unsigned short* __restrict__ AS, float* __restrict__ ssq,
    float* __restrict__ out_idx, int l) {
  __shared__ float rrow[256];
  __shared__ float gm_s;
  __shared__ int list[CAP];
  __shared__ int lcnt;
  __shared__ float wbv[4];
  __shared__ int wbk[4];
  __shared__ int sbk;
  __shared__ float wsum[4];

  int n = blockIdx.x, tid = threadIdx.x;
  int w = tid >> 6, lane = tid & 63;
  rrow[tid] = r[(n << 8) + tid];
  if (tid == 0) lcnt = 0;
  if (tid < 64) {
    float v = (lane < 32) ? pval[n * 32 + lane] : NEGINF;
#pragma unroll
    for (int off = 1; off < 32; off <<= 1) v = fmaxf(v, __shfl_xor(v, off));
    if (tid == 0) gm_s = v;
  }
  __syncthreads();

  int c = cnt[n];
  const float* cbl = cb + ((size_t)l << 20);
  const float* invl = inv + (l << 12);
  float bv = NEGINF; int bk = 0x7fffffff;
  float4 rv4 = *(const float4*)(rrow + lane * 4);

  if (c <= CAP) {
    float thr = gm_s - MARGIN * rnorm[n];
    if (tid < c) {
      float v = cval[n * CAP + tid];
      if (v >= thr) { int p = atomicAdd(&lcnt, 1); list[p] = cand[n * CAP + tid]; }
    }
    __syncthreads();
    int m = lcnt;
    for (int j = w; j < m; j += 4) {          // wave-parallel exact dots
      int k = list[j];
      float4 e4 = *(const float4*)(cbl + ((size_t)k << 8) + lane * 4);
      float p = rv4.x * e4.x + rv4.y * e4.y + rv4.z * e4.z + rv4.w * e4.w;
#pragma unroll
      for (int off = 32; off; off >>= 1) p += __shfl_xor(p, off);
      float s = p * invl[k];
      if (s > bv || (s == bv && k < bk)) { bv = s; bk = k; }
    }
  } else {
    __syncthreads();                           // keep barrier count uniform
    // coalesced full exact scan: wave w handles rows 4*kk + w
    for (int kk = 0; kk < 1024; ++kk) {
      int k = kk * 4 + w;
      float4 e4 = *(const float4*)(cbl + ((size_t)k << 8) + lane * 4);
      float p = rv4.x * e4.x + rv4.y * e4.y + rv4.z * e4.z + rv4.w * e4.w;
#pragma unroll
      for (int off = 32; off; off >>= 1) p += __shfl_xor(p, off);
      float s = p * invl[k];
      if (s > bv || (s == bv && k < bk)) { bv = s; bk = k; }
    }
  }
  if (lane == 0) { wbv[w] = bv; wbk[w] = bk; }
  __syncthreads();
  if (tid == 0) {
    float v0 = wbv[0]; int i0 = wbk[0];
#pragma unroll
    for (int ww = 1; ww < 4; ++ww) {
      float ov = wbv[ww]; int oi = wbk[ww];
      if (ov > v0 || (ov == v0 && oi < i0)) { v0 = ov; i0 = oi; }
    }
    sbk = i0;
    out_idx[(l << 12) + n] = (float)i0;
  }
  __syncthreads();

  // ---- residual update + next-level A split ----
  int ii = sbk;
  float e = cbl[((size_t)ii << 8) + tid];
  float rvv = rrow[tid] - e;
  r[(n << 8) + tid] = rvv;
  AS[(n << 8) + tid] = f2bf(rvv);
  float sq = rvv * rvv;
#pragma unroll
  for (int off = 32; off; off >>= 1) sq += __shfl_xor(sq, off);
  if (lane == 0) wsum[w] = sq;
  __syncthreads();
  if (tid == 0) {
    float tot = (wsum[0] + wsum[1]) + (wsum[2] + wsum[3]);
    ssq[(l << 12) + n] = tot;
    rnorm[n] = sqrtf(tot);
    cnt[n] = 0;
  }
}

// ---- qloss: fixed-order reduction ----
__global__ __launch_bounds__(256) void k_qloss(const float* __restrict__ ssq,
                                               float* __restrict__ out) {
  __shared__ float wsum[4];
  int tid = threadIdx.x;
  float q = 0.f;
  for (int l = 0; l < 4; ++l) {
    float p = 0.f;
#pragma unroll
    for (int i = 0; i < 16; ++i) p += ssq[l * 4096 + i * 256 + tid];
    int lane = tid & 63, w = tid >> 6;
#pragma unroll
    for (int off = 32; off; off >>= 1) p += __shfl_xor(p, off);
    if (lane == 0) wsum[w] = p;
    __syncthreads();
    float tot = (wsum[0] + wsum[1]) + (wsum[2] + wsum[3]);
    q += BETA * (tot * (1.0f / (4096.0f * 256.0f)));
    __syncthreads();
  }
  if (tid == 0) out[1048576 + 16384] = q;
}

// ---- z_q_st = z - residual_final ----
__global__ __launch_bounds__(256) void k_writeq(const float* __restrict__ z,
                                                const float* __restrict__ r,
                                                float* __restrict__ out) {
  __shared__ float t[32][33];
  int id = blockIdx.x;
  int b = id >> 8; int rem = id & 255; int ct = rem >> 5; int ht = rem & 31;
  int c0 = ct * 32, h0 = ht * 32;
  int col = threadIdx.x & 31, row0 = threadIdx.x >> 5;
#pragma unroll
  for (int p = 0; p < 4; ++p) {
    int row = row0 + p * 8;
    t[row][col] = r[(b * 1024 + h0 + row) * 256 + c0 + col];
  }
  __syncthreads();
#pragma unroll
  for (int p = 0; p < 4; ++p) {
    int row = row0 + p * 8;
    int o = ((b * 256 + c0 + row) << 10) + h0 + col;
    out[o] = z[o] - t[col][row];
  }
}

extern "C" void kernel_launch(void* const* d_in, const int* in_sizes, int n_in,
                              void* d_out, int out_size, void* d_ws, size_t ws_size,
                              hipStream_t stream) {
  const float* z  = (const float*)d_in[0];
  const float* cb = (const float*)d_in[1];
  float* out = (float*)d_out;
  float* ws  = (float*)d_ws;

  unsigned short* AS = (unsigned short*)(ws + OFF_AS);
  unsigned short* BS = (unsigned short*)(ws + OFF_BS);
  float* r     = ws + OFF_R;
  float* inv   = ws + OFF_INV;
  float* pval  = ws + OFF_PV;
  float* rnorm = ws + OFF_RN;
  int*   cnt   = (int*)(ws + OFF_CNT);
  int*   cand  = (int*)(ws + OFF_CAND);
  float* cval  = ws + OFF_CVAL;
  float* ssq   = ws + OFF_SSQ;

  k_prep_r<<<1024, 256, 0, stream>>>(z, r);
  k_prep_inv<<<4096, 256, 0, stream>>>(cb, inv);
  k_bsplit_all<<<16384, 256, 0, stream>>>(cb, inv, BS);
  k_split_a<<<4096, 256, 0, stream>>>(r, AS, rnorm, cnt);
  for (int l = 0; l < 4; ++l) {
    k_gemm_argmax<<<1024, 256, 0, stream>>>(AS, BS + (size_t)l * 4096 * 256,
                                            pval, rnorm, cnt, cand, cval);
    k_refine_update<<<4096, 256, 0, stream>>>(cb, inv, r, pval, rnorm, cnt,
                                              cand, cval, AS, ssq,
                                              out + 1048576, l);
  }
  k_qloss<<<1, 256, 0, stream>>>(ssq, out);
  k_writeq<<<1024, 256, 0, stream>>>(z, r, out);
}